// Round 2
// baseline (13619.373 us; speedup 1.0000x reference)
//
#include <hip/hip_runtime.h>

// -------------------- degree / dinv --------------------

__global__ void deg_count(const int* __restrict__ dst, int* __restrict__ deg, int E) {
    int i = blockIdx.x * blockDim.x + threadIdx.x;
    int stride = gridDim.x * blockDim.x;
    for (; i < E; i += stride) {
        atomicAdd(&deg[dst[i]], 1);
    }
}

__global__ void dinv_kernel(const int* __restrict__ deg, float* __restrict__ dinv, int n) {
    int i = blockIdx.x * blockDim.x + threadIdx.x;
    if (i < n) {
        // self-loop adds 1; deg >= 1 guaranteed
        dinv[i] = rsqrtf((float)(deg[i] + 1));
    }
}

// -------------------- fp32 tiled GEMM with fused epilogue --------------------
// C  = A @ B                      [M,K]x[K,N]
// C2 = bias + dinv[row]^2 * C     (self-loop init of aggregation buffer)
// if relu_a: A is max(A,0) on load (used for layer-2 reading pre-activation A1)

__global__ __launch_bounds__(256) void gemm_fused(
        const float* __restrict__ A, const float* __restrict__ B,
        float* __restrict__ C, float* __restrict__ C2,
        const float* __restrict__ dinv, const float* __restrict__ bias,
        int M, int N, int K, int relu_a) {
    __shared__ float As[16][64];
    __shared__ float Bs[16][64];

    const int tid = threadIdx.x;
    const int tx = tid & 15;       // 0..15
    const int ty = tid >> 4;       // 0..15
    const int brow = blockIdx.x * 64;
    const int bcol = blockIdx.y * 64;

    // A-tile load mapping: 64 rows x 16 cols, float4 per thread
    const int arow  = tid >> 2;          // 0..63
    const int acol4 = (tid & 3) << 2;    // 0,4,8,12
    // B-tile load mapping: 16 rows x 64 cols, float4 per thread
    const int brow_l = tid >> 4;         // 0..15
    const int bcol4  = (tid & 15) << 2;  // 0..60

    float acc[4][4] = {};

    for (int k0 = 0; k0 < K; k0 += 16) {
        int gr = brow + arow;
        float4 av;
        if (gr < M) {
            av = *(const float4*)&A[(size_t)gr * K + k0 + acol4];
            if (relu_a) {
                av.x = fmaxf(av.x, 0.0f); av.y = fmaxf(av.y, 0.0f);
                av.z = fmaxf(av.z, 0.0f); av.w = fmaxf(av.w, 0.0f);
            }
        } else {
            av = make_float4(0.f, 0.f, 0.f, 0.f);
        }
        As[acol4 + 0][arow] = av.x;
        As[acol4 + 1][arow] = av.y;
        As[acol4 + 2][arow] = av.z;
        As[acol4 + 3][arow] = av.w;

        float4 bv = *(const float4*)&B[(size_t)(k0 + brow_l) * N + bcol + bcol4];
        *(float4*)&Bs[brow_l][bcol4] = bv;

        __syncthreads();

        #pragma unroll
        for (int k = 0; k < 16; ++k) {
            float4 a = *(const float4*)&As[k][ty << 2];
            float4 b = *(const float4*)&Bs[k][tx << 2];
            float ar[4] = {a.x, a.y, a.z, a.w};
            float br[4] = {b.x, b.y, b.z, b.w};
            #pragma unroll
            for (int i = 0; i < 4; ++i)
                #pragma unroll
                for (int j = 0; j < 4; ++j)
                    acc[i][j] += ar[i] * br[j];
        }
        __syncthreads();
    }

    float4 bb = *(const float4*)&bias[bcol + (tx << 2)];
    #pragma unroll
    for (int i = 0; i < 4; ++i) {
        int gr = brow + (ty << 2) + i;
        if (gr < M) {
            float4 v = make_float4(acc[i][0], acc[i][1], acc[i][2], acc[i][3]);
            *(float4*)&C[(size_t)gr * N + bcol + (tx << 2)] = v;
            float d  = dinv[gr];
            float c2 = d * d;
            float4 v2 = make_float4(bb.x + c2 * v.x, bb.y + c2 * v.y,
                                    bb.z + c2 * v.z, bb.w + c2 * v.w);
            *(float4*)&C2[(size_t)gr * N + bcol + (tx << 2)] = v2;
        }
    }
}

// -------------------- edge scatter (one wave per edge) --------------------
// A[dst] += dinv[src]*dinv[dst] * H[src]   for each edge, C columns (256 or 128)

__global__ __launch_bounds__(256) void scatter_edges(
        const int* __restrict__ src, const int* __restrict__ dst,
        const float* __restrict__ dinv, const float* __restrict__ H,
        float* __restrict__ A, int E, int C) {
    int gtid = blockIdx.x * blockDim.x + threadIdx.x;
    int wave = gtid >> 6;
    int lane = threadIdx.x & 63;
    int nwaves = (gridDim.x * blockDim.x) >> 6;

    if (C == 256) {
        for (int e = wave; e < E; e += nwaves) {
            int s = src[e];
            int d = dst[e];
            float coef = dinv[s] * dinv[d];
            float4 h = *(const float4*)&H[(size_t)s * 256 + (lane << 2)];
            float* a = &A[(size_t)d * 256 + (lane << 2)];
            atomicAdd(a + 0, coef * h.x);
            atomicAdd(a + 1, coef * h.y);
            atomicAdd(a + 2, coef * h.z);
            atomicAdd(a + 3, coef * h.w);
        }
    } else { // C == 128
        for (int e = wave; e < E; e += nwaves) {
            int s = src[e];
            int d = dst[e];
            float coef = dinv[s] * dinv[d];
            float2 h = *(const float2*)&H[(size_t)s * 128 + (lane << 1)];
            float* a = &A[(size_t)d * 128 + (lane << 1)];
            atomicAdd(a + 0, coef * h.x);
            atomicAdd(a + 1, coef * h.y);
        }
    }
}

// -------------------- launch --------------------

extern "C" void kernel_launch(void* const* d_in, const int* in_sizes, int n_in,
                              void* d_out, int out_size, void* d_ws, size_t ws_size,
                              hipStream_t stream) {
    const float* x        = (const float*)d_in[0];
    const int*   ei       = (const int*)d_in[1];   // int64 in reference -> int32 from harness
    const float* W1       = (const float*)d_in[2];
    const float* b1       = (const float*)d_in[3];
    const float* W2       = (const float*)d_in[4];
    const float* b2       = (const float*)d_in[5];
    float* out            = (float*)d_out;

    const int E   = in_sizes[1] / 2;               // 3,200,000
    const int HID = in_sizes[3];                   // 256
    const int IN  = in_sizes[2] / HID;             // 256
    const int OUT = in_sizes[5];                   // 128
    const int N   = in_sizes[0] / IN;              // 100,000

    char* ws = (char*)d_ws;
    int*   deg  = (int*)ws;                                  // N ints
    float* dinv = (float*)(ws + (1 << 20));                  // N floats
    float* H    = (float*)(ws + (2 << 20));                  // N*256 floats (reused for H2)
    float* A1   = (float*)(ws + (size_t)(2 << 20) + (size_t)N * HID * sizeof(float));

    const int* e_src = ei;
    const int* e_dst = ei + E;

    // 1) degrees -> dinv
    hipMemsetAsync(deg, 0, (size_t)N * sizeof(int), stream);
    deg_count<<<2048, 256, 0, stream>>>(e_dst, deg, E);
    dinv_kernel<<<(N + 255) / 256, 256, 0, stream>>>(deg, dinv, N);

    // 2) layer 1: H = X@W1 ; A1 = b1 + dinv^2*H
    {
        dim3 grid((N + 63) / 64, HID / 64);
        gemm_fused<<<grid, 256, 0, stream>>>(x, W1, H, A1, dinv, b1, N, HID, IN, 0);
    }
    scatter_edges<<<4096, 256, 0, stream>>>(e_src, e_dst, dinv, H, A1, E, HID);

    // 3) layer 2: H2 = relu(A1)@W2 ; out = b2 + dinv^2*H2   (H2 reuses H buffer)
    {
        dim3 grid((N + 63) / 64, OUT / 64);
        gemm_fused<<<grid, 256, 0, stream>>>(A1, W2, H, out, dinv, b2, N, OUT, HID, 1);
    }
    scatter_edges<<<4096, 256, 0, stream>>>(e_src, e_dst, dinv, H, out, E, OUT);
}

// Round 3
// 1275.757 us; speedup vs baseline: 10.6755x; 10.6755x over previous
//
#include <hip/hip_runtime.h>

// ==================== degree / dinv ====================

__global__ void deg_count(const int* __restrict__ dst, int* __restrict__ deg, int E) {
    int i = blockIdx.x * blockDim.x + threadIdx.x;
    int stride = gridDim.x * blockDim.x;
    for (; i < E; i += stride) atomicAdd(&deg[dst[i]], 1);
}

__global__ void dinv_kernel(const int* __restrict__ deg, float* __restrict__ dinv, int n) {
    int i = blockIdx.x * blockDim.x + threadIdx.x;
    if (i < n) dinv[i] = rsqrtf((float)(deg[i] + 1));  // +1 self-loop
}

// ==================== exclusive scan (3-kernel) ====================

__global__ void scan_blocks(const int* __restrict__ deg, int* __restrict__ excl,
                            int* __restrict__ block_sums, int n) {
    __shared__ int s[256];
    int t = threadIdx.x;
    int gid = blockIdx.x * 256 + t;
    int v = (gid < n) ? deg[gid] : 0;
    s[t] = v;
    __syncthreads();
    #pragma unroll
    for (int off = 1; off < 256; off <<= 1) {
        int add = (t >= off) ? s[t - off] : 0;
        __syncthreads();
        s[t] += add;
        __syncthreads();
    }
    if (gid < n) excl[gid] = s[t] - v;
    if (t == 255) block_sums[blockIdx.x] = s[255];
}

__global__ void scan_sums(int* __restrict__ block_sums, int nb) {
    __shared__ int s[512];
    int t = threadIdx.x;
    int v = (t < nb) ? block_sums[t] : 0;
    s[t] = v;
    __syncthreads();
    #pragma unroll
    for (int off = 1; off < 512; off <<= 1) {
        int add = (t >= off) ? s[t - off] : 0;
        __syncthreads();
        s[t] += add;
        __syncthreads();
    }
    if (t < nb) block_sums[t] = s[t] - v;  // exclusive
}

__global__ void scan_add(int* __restrict__ excl, const int* __restrict__ block_sums,
                         int n, int E) {
    int gid = blockIdx.x * 256 + threadIdx.x;
    if (gid < n) excl[gid] += block_sums[gid >> 8];
    if (gid == n) excl[n] = E;
}

// ==================== CSR fill (int atomics only) ====================

__global__ void fill_csr(const int* __restrict__ src, const int* __restrict__ dst,
                         const int* __restrict__ row_ptr, int* __restrict__ cursor,
                         int* __restrict__ sorted_src, int E) {
    int i = blockIdx.x * blockDim.x + threadIdx.x;
    int stride = gridDim.x * blockDim.x;
    for (; i < E; i += stride) {
        int d = dst[i];
        int pos = row_ptr[d] + atomicAdd(&cursor[d], 1);
        sorted_src[pos] = src[i];
    }
}

// ==================== fp32 tiled GEMM, epilogue: Hs = dinv[row] * (A@B) ====================

__global__ __launch_bounds__(256) void gemm_scaled(
        const float* __restrict__ A, const float* __restrict__ B,
        float* __restrict__ Hs, const float* __restrict__ dinv,
        int M, int N, int K) {
    __shared__ float As[16][64];
    __shared__ float Bs[16][64];

    const int tid = threadIdx.x;
    const int tx = tid & 15;
    const int ty = tid >> 4;
    const int brow = blockIdx.x * 64;
    const int bcol = blockIdx.y * 64;

    const int arow  = tid >> 2;
    const int acol4 = (tid & 3) << 2;
    const int brow_l = tid >> 4;
    const int bcol4  = (tid & 15) << 2;

    float acc[4][4] = {};

    for (int k0 = 0; k0 < K; k0 += 16) {
        int gr = brow + arow;
        float4 av = (gr < M) ? *(const float4*)&A[(size_t)gr * K + k0 + acol4]
                             : make_float4(0.f, 0.f, 0.f, 0.f);
        As[acol4 + 0][arow] = av.x;
        As[acol4 + 1][arow] = av.y;
        As[acol4 + 2][arow] = av.z;
        As[acol4 + 3][arow] = av.w;

        *(float4*)&Bs[brow_l][bcol4] =
            *(const float4*)&B[(size_t)(k0 + brow_l) * N + bcol + bcol4];

        __syncthreads();

        #pragma unroll
        for (int k = 0; k < 16; ++k) {
            float4 a = *(const float4*)&As[k][ty << 2];
            float4 b = *(const float4*)&Bs[k][tx << 2];
            float ar[4] = {a.x, a.y, a.z, a.w};
            float br[4] = {b.x, b.y, b.z, b.w};
            #pragma unroll
            for (int i = 0; i < 4; ++i)
                #pragma unroll
                for (int j = 0; j < 4; ++j)
                    acc[i][j] += ar[i] * br[j];
        }
        __syncthreads();
    }

    #pragma unroll
    for (int i = 0; i < 4; ++i) {
        int gr = brow + (ty << 2) + i;
        if (gr < M) {
            float dv = dinv[gr];
            float4 v = make_float4(dv * acc[i][0], dv * acc[i][1],
                                   dv * acc[i][2], dv * acc[i][3]);
            *(float4*)&Hs[(size_t)gr * N + bcol + (tx << 2)] = v;
        }
    }
}

// ==================== pull aggregation: one wave per node ====================
// out[d] = act( bias + dinv[d] * (Hs[d] + sum_{s in in(d)} Hs[s]) )

__global__ __launch_bounds__(256) void agg_pull_256(
        const int* __restrict__ row_ptr, const int* __restrict__ sorted_src,
        const float* __restrict__ dinv, const float* __restrict__ Hs,
        const float* __restrict__ bias, float* __restrict__ out,
        int N, int relu) {
    int node = blockIdx.x * 4 + (threadIdx.x >> 6);
    int lane = threadIdx.x & 63;
    if (node >= N) return;

    int r0 = row_ptr[node], r1 = row_ptr[node + 1];
    int c = lane << 2;
    float4 acc = *(const float4*)&Hs[(size_t)node * 256 + c];

    int i = r0;
    for (; i + 4 <= r1; i += 4) {
        int s0 = sorted_src[i], s1 = sorted_src[i + 1];
        int s2 = sorted_src[i + 2], s3 = sorted_src[i + 3];
        float4 h0 = *(const float4*)&Hs[(size_t)s0 * 256 + c];
        float4 h1 = *(const float4*)&Hs[(size_t)s1 * 256 + c];
        float4 h2 = *(const float4*)&Hs[(size_t)s2 * 256 + c];
        float4 h3 = *(const float4*)&Hs[(size_t)s3 * 256 + c];
        acc.x += (h0.x + h1.x) + (h2.x + h3.x);
        acc.y += (h0.y + h1.y) + (h2.y + h3.y);
        acc.z += (h0.z + h1.z) + (h2.z + h3.z);
        acc.w += (h0.w + h1.w) + (h2.w + h3.w);
    }
    for (; i < r1; ++i) {
        int s = sorted_src[i];
        float4 h = *(const float4*)&Hs[(size_t)s * 256 + c];
        acc.x += h.x; acc.y += h.y; acc.z += h.z; acc.w += h.w;
    }

    float dv = dinv[node];
    float4 bb = *(const float4*)&bias[c];
    float4 o = make_float4(bb.x + dv * acc.x, bb.y + dv * acc.y,
                           bb.z + dv * acc.z, bb.w + dv * acc.w);
    if (relu) {
        o.x = fmaxf(o.x, 0.f); o.y = fmaxf(o.y, 0.f);
        o.z = fmaxf(o.z, 0.f); o.w = fmaxf(o.w, 0.f);
    }
    *(float4*)&out[(size_t)node * 256 + c] = o;
}

__global__ __launch_bounds__(256) void agg_pull_128(
        const int* __restrict__ row_ptr, const int* __restrict__ sorted_src,
        const float* __restrict__ dinv, const float* __restrict__ Hs,
        const float* __restrict__ bias, float* __restrict__ out,
        int N) {
    int node = blockIdx.x * 4 + (threadIdx.x >> 6);
    int lane = threadIdx.x & 63;
    if (node >= N) return;

    int r0 = row_ptr[node], r1 = row_ptr[node + 1];
    int c = lane << 1;
    float2 acc = *(const float2*)&Hs[(size_t)node * 128 + c];

    int i = r0;
    for (; i + 4 <= r1; i += 4) {
        int s0 = sorted_src[i], s1 = sorted_src[i + 1];
        int s2 = sorted_src[i + 2], s3 = sorted_src[i + 3];
        float2 h0 = *(const float2*)&Hs[(size_t)s0 * 128 + c];
        float2 h1 = *(const float2*)&Hs[(size_t)s1 * 128 + c];
        float2 h2 = *(const float2*)&Hs[(size_t)s2 * 128 + c];
        float2 h3 = *(const float2*)&Hs[(size_t)s3 * 128 + c];
        acc.x += (h0.x + h1.x) + (h2.x + h3.x);
        acc.y += (h0.y + h1.y) + (h2.y + h3.y);
    }
    for (; i < r1; ++i) {
        int s = sorted_src[i];
        float2 h = *(const float2*)&Hs[(size_t)s * 128 + c];
        acc.x += h.x; acc.y += h.y;
    }

    float dv = dinv[node];
    float2 bb = *(const float2*)&bias[c];
    float2 o = make_float2(bb.x + dv * acc.x, bb.y + dv * acc.y);
    *(float2*)&out[(size_t)node * 128 + c] = o;
}

// ==================== launch ====================

extern "C" void kernel_launch(void* const* d_in, const int* in_sizes, int n_in,
                              void* d_out, int out_size, void* d_ws, size_t ws_size,
                              hipStream_t stream) {
    const float* x   = (const float*)d_in[0];
    const int*   ei  = (const int*)d_in[1];   // int64 ref -> int32 from harness
    const float* W1  = (const float*)d_in[2];
    const float* b1  = (const float*)d_in[3];
    const float* W2  = (const float*)d_in[4];
    const float* b2  = (const float*)d_in[5];
    float* out       = (float*)d_out;

    const int E   = in_sizes[1] / 2;           // 3,200,000
    const int HID = in_sizes[3];               // 256
    const int IN  = in_sizes[2] / HID;         // 256
    const int OUT = in_sizes[5];               // 128
    const int N   = in_sizes[0] / IN;          // 100,000

    char* ws = (char*)d_ws;
    int*   row_ptr    = (int*)ws;                              // N+1 ints  (~400KB)
    int*   cursor     = (int*)(ws + (512 << 10));              // N ints (doubles as deg)
    float* dinv       = (float*)(ws + (1 << 20));              // N floats
    int*   block_sums = (int*)(ws + ((1 << 20) + (512 << 10)));// ~400 ints
    int*   sorted_src = (int*)(ws + (2 << 20));                // E ints (12.8MB)
    float* Hs         = (float*)(ws + (16 << 20));             // N*256 f32 (102.4MB)
    float* A1         = (float*)(ws + (16 << 20) + (size_t)N * 256 * sizeof(float));

    const int* e_src = ei;
    const int* e_dst = ei + E;

    const int nb_scan = (N + 255) / 256;  // 391

    // ---- CSR build ----
    hipMemsetAsync(cursor, 0, (size_t)N * sizeof(int), stream);
    deg_count<<<2048, 256, 0, stream>>>(e_dst, cursor, E);          // cursor = deg
    dinv_kernel<<<nb_scan, 256, 0, stream>>>(cursor, dinv, N);
    scan_blocks<<<nb_scan, 256, 0, stream>>>(cursor, row_ptr, block_sums, N);
    scan_sums<<<1, 512, 0, stream>>>(block_sums, nb_scan);
    scan_add<<<(N + 256) / 256, 256, 0, stream>>>(row_ptr, block_sums, N, E);
    hipMemsetAsync(cursor, 0, (size_t)N * sizeof(int), stream);     // reuse as fill cursor
    fill_csr<<<4096, 256, 0, stream>>>(e_src, e_dst, row_ptr, cursor, sorted_src, E);

    // ---- layer 1: Hs = dinv * (X@W1); A1 = relu(b1 + dinv*(Hs[d] + sum Hs[s])) ----
    {
        dim3 grid((N + 63) / 64, HID / 64);
        gemm_scaled<<<grid, 256, 0, stream>>>(x, W1, Hs, dinv, N, HID, IN);
    }
    agg_pull_256<<<(N + 3) / 4, 256, 0, stream>>>(row_ptr, sorted_src, dinv, Hs, b1, A1, N, 1);

    // ---- layer 2: Hs2 = dinv * (A1@W2) (reuses Hs buffer); out = b2 + dinv*(...) ----
    {
        dim3 grid((N + 63) / 64, OUT / 64);
        gemm_scaled<<<grid, 256, 0, stream>>>(A1, W2, Hs, dinv, N, OUT, HID);
    }
    agg_pull_128<<<(N + 3) / 4, 256, 0, stream>>>(row_ptr, sorted_src, dinv, Hs, b2, out, N);
}

// Round 4
// 765.984 us; speedup vs baseline: 17.7802x; 1.6655x over previous
//
#include <hip/hip_runtime.h>

using f32x4 = __attribute__((ext_vector_type(4))) float;
using s16x8 = __attribute__((ext_vector_type(8))) short;

static __device__ __forceinline__ unsigned short f2bf(float f) {
    union { float f; unsigned u; } v; v.f = f;
    unsigned r = v.u + 0x7fffu + ((v.u >> 16) & 1u);  // round-to-nearest-even
    return (unsigned short)(r >> 16);
}
static __device__ __forceinline__ float bf2f(unsigned short h) {
    union { unsigned u; float f; } v; v.u = ((unsigned)h) << 16;
    return v.f;
}

// ==================== degree / dinv ====================

__global__ void deg_count(const int* __restrict__ dst, int* __restrict__ deg, int E) {
    int i = blockIdx.x * blockDim.x + threadIdx.x;
    int stride = gridDim.x * blockDim.x;
    for (; i < E; i += stride) atomicAdd(&deg[dst[i]], 1);
}

__global__ void dinv_kernel(const int* __restrict__ deg, float* __restrict__ dinv, int n) {
    int i = blockIdx.x * blockDim.x + threadIdx.x;
    if (i < n) dinv[i] = rsqrtf((float)(deg[i] + 1));  // +1 self-loop
}

// ==================== exclusive scan (3-kernel) ====================

__global__ void scan_blocks(const int* __restrict__ deg, int* __restrict__ excl,
                            int* __restrict__ block_sums, int n) {
    __shared__ int s[256];
    int t = threadIdx.x;
    int gid = blockIdx.x * 256 + t;
    int v = (gid < n) ? deg[gid] : 0;
    s[t] = v;
    __syncthreads();
    #pragma unroll
    for (int off = 1; off < 256; off <<= 1) {
        int add = (t >= off) ? s[t - off] : 0;
        __syncthreads();
        s[t] += add;
        __syncthreads();
    }
    if (gid < n) excl[gid] = s[t] - v;
    if (t == 255) block_sums[blockIdx.x] = s[255];
}

__global__ void scan_sums(int* __restrict__ block_sums, int nb) {
    __shared__ int s[512];
    int t = threadIdx.x;
    int v = (t < nb) ? block_sums[t] : 0;
    s[t] = v;
    __syncthreads();
    #pragma unroll
    for (int off = 1; off < 512; off <<= 1) {
        int add = (t >= off) ? s[t - off] : 0;
        __syncthreads();
        s[t] += add;
        __syncthreads();
    }
    if (t < nb) block_sums[t] = s[t] - v;
}

__global__ void scan_add(int* __restrict__ excl, const int* __restrict__ block_sums,
                         int n, int E) {
    int gid = blockIdx.x * 256 + threadIdx.x;
    if (gid < n) excl[gid] += block_sums[gid >> 8];
    if (gid == n) excl[n] = E;
}

// ==================== CSR fill ====================

__global__ void fill_csr(const int* __restrict__ src, const int* __restrict__ dst,
                         const int* __restrict__ row_ptr, int* __restrict__ cursor,
                         int* __restrict__ sorted_src, int E) {
    int i = blockIdx.x * blockDim.x + threadIdx.x;
    int stride = gridDim.x * blockDim.x;
    for (; i < E; i += stride) {
        int d = dst[i];
        int pos = row_ptr[d] + atomicAdd(&cursor[d], 1);
        sorted_src[pos] = src[i];
    }
}

// ==================== f32 -> bf16 conversion ====================

__global__ void f32_to_bf16(const float* __restrict__ in, unsigned short* __restrict__ out,
                            int n4) {  // n4 = n/4
    int i = blockIdx.x * blockDim.x + threadIdx.x;
    int stride = gridDim.x * blockDim.x;
    for (; i < n4; i += stride) {
        float4 v = *(const float4*)&in[(size_t)i * 4];
        ushort4 o = make_ushort4(f2bf(v.x), f2bf(v.y), f2bf(v.z), f2bf(v.w));
        *(ushort4*)&out[(size_t)i * 4] = o;
    }
}

// ==================== bf16 MFMA GEMM: C = bf16( dinv[row] * (A@B) ) ====================
// A [M][K] bf16, B [K][N] bf16, C [M][N] bf16. Block: 256 thr (4 waves 2x2),
// tile 128x64, BK=32, mfma_f32_16x16x32_bf16.

__global__ __launch_bounds__(256) void gemm_bf16_mfma(
        const unsigned short* __restrict__ A, const unsigned short* __restrict__ B,
        unsigned short* __restrict__ C, const float* __restrict__ dinv,
        int M, int N, int K) {
    __shared__ __align__(16) short As[128][40];  // pad 32->40: 80B stride, 2-way free
    __shared__ __align__(16) short Bt[64][40];   // B transposed [col][k]

    const int tid  = threadIdx.x;
    const int lane = tid & 63;
    const int wave = tid >> 6;
    const int wm = wave >> 1, wn = wave & 1;
    const int brow = blockIdx.x * 128;
    const int bcol = blockIdx.y * 64;

    const int fr = lane & 15;          // row(A-frag) / col(B-frag) / col(D)
    const int kk = (lane >> 4) * 8;    // k-offset of this lane's 8 elements

    f32x4 acc[4][2] = {};

    const int ar = tid >> 2;           // A-stage row 0..63 (two passes)
    const int ac = (tid & 3) * 8;      // A-stage k-chunk
    const int bk = tid >> 3;           // B-stage k 0..31
    const int bc = (tid & 7) * 8;      // B-stage col-chunk

    for (int k0 = 0; k0 < K; k0 += 32) {
        #pragma unroll
        for (int rr = 0; rr < 128; rr += 64) {
            int gr = brow + ar + rr;
            s16x8 v = {};
            if (gr < M) v = *(const s16x8*)&A[(size_t)gr * K + k0 + ac];
            *(s16x8*)&As[ar + rr][ac] = v;
        }
        {
            s16x8 v = *(const s16x8*)&B[(size_t)(k0 + bk) * N + bcol + bc];
            #pragma unroll
            for (int j = 0; j < 8; ++j) Bt[bc + j][bk] = v[j];
        }
        __syncthreads();

        s16x8 af[4], bv[2];
        #pragma unroll
        for (int fm = 0; fm < 4; ++fm)
            af[fm] = *(const s16x8*)&As[wm * 64 + fm * 16 + fr][kk];
        #pragma unroll
        for (int fn = 0; fn < 2; ++fn)
            bv[fn] = *(const s16x8*)&Bt[wn * 32 + fn * 16 + fr][kk];
        #pragma unroll
        for (int fm = 0; fm < 4; ++fm)
            #pragma unroll
            for (int fn = 0; fn < 2; ++fn)
                acc[fm][fn] = __builtin_amdgcn_mfma_f32_16x16x32_bf16(
                    af[fm], bv[fn], acc[fm][fn], 0, 0, 0);
        __syncthreads();
    }

    // C/D layout: col = lane&15, row = (lane>>4)*4 + reg  [m89-verified]
    const int orow = (lane >> 4) * 4;
    #pragma unroll
    for (int fm = 0; fm < 4; ++fm) {
        #pragma unroll
        for (int reg = 0; reg < 4; ++reg) {
            int gr = brow + wm * 64 + fm * 16 + orow + reg;
            if (gr < M) {
                float dv = dinv[gr];
                #pragma unroll
                for (int fn = 0; fn < 2; ++fn) {
                    int gc = bcol + wn * 32 + fn * 16 + fr;
                    C[(size_t)gr * N + gc] = f2bf(dv * acc[fm][fn][reg]);
                }
            }
        }
    }
}

// ==================== pull aggregation (bf16 table) ====================
// layer1: A1b = bf16( relu( b + dinv[d]*(Hs[d] + sum Hs[s]) ) )

__global__ __launch_bounds__(256) void agg_pull_256_bf16(
        const int* __restrict__ row_ptr, const int* __restrict__ sorted_src,
        const float* __restrict__ dinv, const unsigned short* __restrict__ Hs,
        const float* __restrict__ bias, unsigned short* __restrict__ outb, int N) {
    int node = blockIdx.x * 4 + (threadIdx.x >> 6);
    int lane = threadIdx.x & 63;
    if (node >= N) return;

    int r0 = row_ptr[node], r1 = row_ptr[node + 1];
    int c = lane << 2;
    ushort4 hv = *(const ushort4*)&Hs[(size_t)node * 256 + c];
    float a0 = bf2f(hv.x), a1 = bf2f(hv.y), a2 = bf2f(hv.z), a3 = bf2f(hv.w);

    int i = r0;
    for (; i + 4 <= r1; i += 4) {
        int s0 = sorted_src[i], s1 = sorted_src[i + 1];
        int s2 = sorted_src[i + 2], s3 = sorted_src[i + 3];
        ushort4 h0 = *(const ushort4*)&Hs[(size_t)s0 * 256 + c];
        ushort4 h1 = *(const ushort4*)&Hs[(size_t)s1 * 256 + c];
        ushort4 h2 = *(const ushort4*)&Hs[(size_t)s2 * 256 + c];
        ushort4 h3 = *(const ushort4*)&Hs[(size_t)s3 * 256 + c];
        a0 += (bf2f(h0.x) + bf2f(h1.x)) + (bf2f(h2.x) + bf2f(h3.x));
        a1 += (bf2f(h0.y) + bf2f(h1.y)) + (bf2f(h2.y) + bf2f(h3.y));
        a2 += (bf2f(h0.z) + bf2f(h1.z)) + (bf2f(h2.z) + bf2f(h3.z));
        a3 += (bf2f(h0.w) + bf2f(h1.w)) + (bf2f(h2.w) + bf2f(h3.w));
    }
    for (; i < r1; ++i) {
        int s = sorted_src[i];
        ushort4 h = *(const ushort4*)&Hs[(size_t)s * 256 + c];
        a0 += bf2f(h.x); a1 += bf2f(h.y); a2 += bf2f(h.z); a3 += bf2f(h.w);
    }

    float dv = dinv[node];
    float4 bb = *(const float4*)&bias[c];
    float o0 = fmaxf(bb.x + dv * a0, 0.f);
    float o1 = fmaxf(bb.y + dv * a1, 0.f);
    float o2 = fmaxf(bb.z + dv * a2, 0.f);
    float o3 = fmaxf(bb.w + dv * a3, 0.f);
    *(ushort4*)&outb[(size_t)node * 256 + c] = make_ushort4(f2bf(o0), f2bf(o1), f2bf(o2), f2bf(o3));
}

// layer2: out_f32 = b + dinv[d]*(Hs[d] + sum Hs[s])

__global__ __launch_bounds__(256) void agg_pull_128_bf16(
        const int* __restrict__ row_ptr, const int* __restrict__ sorted_src,
        const float* __restrict__ dinv, const unsigned short* __restrict__ Hs,
        const float* __restrict__ bias, float* __restrict__ out, int N) {
    int node = blockIdx.x * 4 + (threadIdx.x >> 6);
    int lane = threadIdx.x & 63;
    if (node >= N) return;

    int r0 = row_ptr[node], r1 = row_ptr[node + 1];
    int c = lane << 1;
    ushort2 hv = *(const ushort2*)&Hs[(size_t)node * 128 + c];
    float a0 = bf2f(hv.x), a1 = bf2f(hv.y);

    int i = r0;
    for (; i + 4 <= r1; i += 4) {
        int s0 = sorted_src[i], s1 = sorted_src[i + 1];
        int s2 = sorted_src[i + 2], s3 = sorted_src[i + 3];
        ushort2 h0 = *(const ushort2*)&Hs[(size_t)s0 * 128 + c];
        ushort2 h1 = *(const ushort2*)&Hs[(size_t)s1 * 128 + c];
        ushort2 h2 = *(const ushort2*)&Hs[(size_t)s2 * 128 + c];
        ushort2 h3 = *(const ushort2*)&Hs[(size_t)s3 * 128 + c];
        a0 += (bf2f(h0.x) + bf2f(h1.x)) + (bf2f(h2.x) + bf2f(h3.x));
        a1 += (bf2f(h0.y) + bf2f(h1.y)) + (bf2f(h2.y) + bf2f(h3.y));
    }
    for (; i < r1; ++i) {
        int s = sorted_src[i];
        ushort2 h = *(const ushort2*)&Hs[(size_t)s * 128 + c];
        a0 += bf2f(h.x); a1 += bf2f(h.y);
    }

    float dv = dinv[node];
    float2 bb = *(const float2*)&bias[c];
    *(float2*)&out[(size_t)node * 128 + c] = make_float2(bb.x + dv * a0, bb.y + dv * a1);
}

// ==================== launch ====================

extern "C" void kernel_launch(void* const* d_in, const int* in_sizes, int n_in,
                              void* d_out, int out_size, void* d_ws, size_t ws_size,
                              hipStream_t stream) {
    const float* x   = (const float*)d_in[0];
    const int*   ei  = (const int*)d_in[1];
    const float* W1  = (const float*)d_in[2];
    const float* b1  = (const float*)d_in[3];
    const float* W2  = (const float*)d_in[4];
    const float* b2  = (const float*)d_in[5];
    float* out       = (float*)d_out;

    const int E   = in_sizes[1] / 2;           // 3,200,000
    const int HID = in_sizes[3];               // 256
    const int IN  = in_sizes[2] / HID;         // 256
    const int OUT = in_sizes[5];               // 128
    const int N   = in_sizes[0] / IN;          // 100,000

    char* ws = (char*)d_ws;
    int*   row_ptr    = (int*)ws;                                   // (N+1) ints
    int*   cursor     = (int*)(ws + (512 << 10));
    float* dinv       = (float*)(ws + (1 << 20));
    int*   block_sums = (int*)(ws + 1572864);
    unsigned short* W1b = (unsigned short*)(ws + 1703936);          // 256*256 bf16
    unsigned short* W2b = (unsigned short*)(ws + 1867776);          // 256*128 bf16
    int*   sorted_src = (int*)(ws + (2 << 20));                     // E ints
    unsigned short* Xb  = (unsigned short*)(ws + ((size_t)16 << 20));   // N*256 bf16 (51.2MB)
    unsigned short* Hsb = (unsigned short*)(ws + ((size_t)70 << 20));   // N*256 bf16
    unsigned short* A1b = (unsigned short*)(ws + ((size_t)126 << 20));  // N*256 bf16

    const int* e_src = ei;
    const int* e_dst = ei + E;
    const int nb_scan = (N + 255) / 256;

    // ---- CSR build + dinv ----
    hipMemsetAsync(cursor, 0, (size_t)N * sizeof(int), stream);
    deg_count<<<2048, 256, 0, stream>>>(e_dst, cursor, E);
    dinv_kernel<<<nb_scan, 256, 0, stream>>>(cursor, dinv, N);
    scan_blocks<<<nb_scan, 256, 0, stream>>>(cursor, row_ptr, block_sums, N);
    scan_sums<<<1, 512, 0, stream>>>(block_sums, nb_scan);
    scan_add<<<(N + 256) / 256, 256, 0, stream>>>(row_ptr, block_sums, N, E);
    hipMemsetAsync(cursor, 0, (size_t)N * sizeof(int), stream);
    fill_csr<<<4096, 256, 0, stream>>>(e_src, e_dst, row_ptr, cursor, sorted_src, E);

    // ---- bf16 conversions ----
    f32_to_bf16<<<2048, 256, 0, stream>>>(x, Xb, N * IN / 4);
    f32_to_bf16<<<32, 256, 0, stream>>>(W1, W1b, IN * HID / 4);
    f32_to_bf16<<<16, 256, 0, stream>>>(W2, W2b, HID * OUT / 4);

    // ---- layer 1 ----
    {
        dim3 grid((N + 127) / 128, HID / 64);
        gemm_bf16_mfma<<<grid, 256, 0, stream>>>(Xb, W1b, Hsb, dinv, N, HID, IN);
    }
    agg_pull_256_bf16<<<(N + 3) / 4, 256, 0, stream>>>(row_ptr, sorted_src, dinv, Hsb, b1, A1b, N);

    // ---- layer 2 ----
    {
        dim3 grid((N + 127) / 128, OUT / 64);
        gemm_bf16_mfma<<<grid, 256, 0, stream>>>(A1b, W2b, Hsb, dinv, N, OUT, HID);
    }
    agg_pull_128_bf16<<<(N + 3) / 4, 256, 0, stream>>>(row_ptr, sorted_src, dinv, Hsb, b2, out, N);
}

// Round 5
// 753.642 us; speedup vs baseline: 18.0714x; 1.0164x over previous
//
#include <hip/hip_runtime.h>

using f32x4 = __attribute__((ext_vector_type(4))) float;
using s16x8 = __attribute__((ext_vector_type(8))) short;

static __device__ __forceinline__ unsigned short f2bf(float f) {
    union { float f; unsigned u; } v; v.f = f;
    unsigned r = v.u + 0x7fffu + ((v.u >> 16) & 1u);  // round-to-nearest-even
    return (unsigned short)(r >> 16);
}
static __device__ __forceinline__ float bf2f(unsigned short h) {
    union { unsigned u; float f; } v; v.u = ((unsigned)h) << 16;
    return v.f;
}

// ==================== degree / dinv ====================

__global__ void deg_count(const int* __restrict__ dst, int* __restrict__ deg, int E4) {
    int i = blockIdx.x * blockDim.x + threadIdx.x;
    int stride = gridDim.x * blockDim.x;
    for (; i < E4; i += stride) {
        int4 d = *(const int4*)&dst[i * 4];
        atomicAdd(&deg[d.x], 1);
        atomicAdd(&deg[d.y], 1);
        atomicAdd(&deg[d.z], 1);
        atomicAdd(&deg[d.w], 1);
    }
}

__global__ void dinv_kernel(const int* __restrict__ deg, float* __restrict__ dinv, int n) {
    int i = blockIdx.x * blockDim.x + threadIdx.x;
    if (i < n) dinv[i] = rsqrtf((float)(deg[i] + 1));  // +1 self-loop
}

// ==================== exclusive scan (3-kernel) ====================

__global__ void scan_blocks(const int* __restrict__ deg, int* __restrict__ excl,
                            int* __restrict__ block_sums, int n) {
    __shared__ int s[256];
    int t = threadIdx.x;
    int gid = blockIdx.x * 256 + t;
    int v = (gid < n) ? deg[gid] : 0;
    s[t] = v;
    __syncthreads();
    #pragma unroll
    for (int off = 1; off < 256; off <<= 1) {
        int add = (t >= off) ? s[t - off] : 0;
        __syncthreads();
        s[t] += add;
        __syncthreads();
    }
    if (gid < n) excl[gid] = s[t] - v;
    if (t == 255) block_sums[blockIdx.x] = s[255];
}

__global__ void scan_sums(int* __restrict__ block_sums, int nb) {
    __shared__ int s[512];
    int t = threadIdx.x;
    int v = (t < nb) ? block_sums[t] : 0;
    s[t] = v;
    __syncthreads();
    #pragma unroll
    for (int off = 1; off < 512; off <<= 1) {
        int add = (t >= off) ? s[t - off] : 0;
        __syncthreads();
        s[t] += add;
        __syncthreads();
    }
    if (t < nb) block_sums[t] = s[t] - v;
}

__global__ void scan_add(int* __restrict__ excl, const int* __restrict__ block_sums,
                         int n, int E) {
    int gid = blockIdx.x * 256 + threadIdx.x;
    if (gid < n) excl[gid] += block_sums[gid >> 8];
    if (gid == n) excl[n] = E;
}

// ==================== CSR fill ====================

__global__ void fill_csr(const int* __restrict__ src, const int* __restrict__ dst,
                         const int* __restrict__ row_ptr, int* __restrict__ cursor,
                         int* __restrict__ sorted_src, int E) {
    int i = blockIdx.x * blockDim.x + threadIdx.x;
    int stride = gridDim.x * blockDim.x;
    for (; i < E; i += stride) {
        int d = dst[i];
        int pos = row_ptr[d] + atomicAdd(&cursor[d], 1);
        sorted_src[pos] = src[i];
    }
}

// ==================== f32 -> bf16 (weights only) ====================

__global__ void f32_to_bf16(const float* __restrict__ in, unsigned short* __restrict__ out,
                            int n4) {
    int i = blockIdx.x * blockDim.x + threadIdx.x;
    int stride = gridDim.x * blockDim.x;
    for (; i < n4; i += stride) {
        float4 v = *(const float4*)&in[(size_t)i * 4];
        *(ushort4*)&out[(size_t)i * 4] = make_ushort4(f2bf(v.x), f2bf(v.y), f2bf(v.z), f2bf(v.w));
    }
}

// ==================== bf16 MFMA GEMM, full-width output tile ====================
// C[M][BN] = bf16( dinv[row] * (A@B) ).  Tile 64 rows x BN cols, BK=32.
// AF32: A is f32, converted to bf16 in-register during LDS staging.
// 256 threads = 4 waves; wave w covers cols [w*BN/4, (w+1)*BN/4).

template<int BN, bool AF32>
__global__ __launch_bounds__(256) void gemm_mfma(
        const void* __restrict__ Av, const unsigned short* __restrict__ B,
        unsigned short* __restrict__ C, const float* __restrict__ dinv,
        int M, int K) {
    constexpr int FN = BN / 64;          // B-fragments per wave (4 or 2)
    __shared__ __align__(16) short As[64][40];   // pad 32->40
    __shared__ __align__(16) short Bt[BN][40];   // B transposed [col][k]

    const int tid  = threadIdx.x;
    const int lane = tid & 63;
    const int wave = tid >> 6;
    const int brow = blockIdx.x * 64;

    const int fr = lane & 15;
    const int kk = (lane >> 4) * 8;

    const int ar = tid >> 2;             // 0..63
    const int ac = (tid & 3) * 8;        // 0,8,16,24
    const int bk = tid >> 3;             // 0..31
    const int bc = (tid & 7) * (BN / 8); // col-chunk base

    f32x4 acc[4][FN] = {};

    for (int k0 = 0; k0 < K; k0 += 32) {
        // ---- stage A (convert if f32) ----
        {
            int gr = brow + ar;
            s16x8 s = {};
            if (gr < M) {
                if constexpr (AF32) {
                    const float* A = (const float*)Av;
                    float4 v0 = *(const float4*)&A[(size_t)gr * K + k0 + ac];
                    float4 v1 = *(const float4*)&A[(size_t)gr * K + k0 + ac + 4];
                    s[0] = (short)f2bf(v0.x); s[1] = (short)f2bf(v0.y);
                    s[2] = (short)f2bf(v0.z); s[3] = (short)f2bf(v0.w);
                    s[4] = (short)f2bf(v1.x); s[5] = (short)f2bf(v1.y);
                    s[6] = (short)f2bf(v1.z); s[7] = (short)f2bf(v1.w);
                } else {
                    const unsigned short* A = (const unsigned short*)Av;
                    s = *(const s16x8*)&A[(size_t)gr * K + k0 + ac];
                }
            }
            *(s16x8*)&As[ar][ac] = s;
        }
        // ---- stage B (transpose into [col][k]) ----
        #pragma unroll
        for (int j2 = 0; j2 < BN / 64; ++j2) {
            s16x8 v = *(const s16x8*)&B[(size_t)(k0 + bk) * BN + bc + j2 * 8];
            #pragma unroll
            for (int j = 0; j < 8; ++j) Bt[bc + j2 * 8 + j][bk] = v[j];
        }
        __syncthreads();

        s16x8 af[4], bv[FN];
        #pragma unroll
        for (int fm = 0; fm < 4; ++fm)
            af[fm] = *(const s16x8*)&As[fm * 16 + fr][kk];
        #pragma unroll
        for (int fn = 0; fn < FN; ++fn)
            bv[fn] = *(const s16x8*)&Bt[wave * (BN / 4) + fn * 16 + fr][kk];
        #pragma unroll
        for (int fm = 0; fm < 4; ++fm)
            #pragma unroll
            for (int fn = 0; fn < FN; ++fn)
                acc[fm][fn] = __builtin_amdgcn_mfma_f32_16x16x32_bf16(
                    af[fm], bv[fn], acc[fm][fn], 0, 0, 0);
        __syncthreads();
    }

    // C/D layout: col = lane&15, row = (lane>>4)*4 + reg  [m89-verified]
    const int orow = (lane >> 4) * 4;
    #pragma unroll
    for (int fm = 0; fm < 4; ++fm) {
        #pragma unroll
        for (int reg = 0; reg < 4; ++reg) {
            int gr = brow + fm * 16 + orow + reg;
            if (gr < M) {
                float dv = dinv[gr];
                #pragma unroll
                for (int fn = 0; fn < FN; ++fn) {
                    int gc = wave * (BN / 4) + fn * 16 + fr;
                    C[(size_t)gr * BN + gc] = f2bf(dv * acc[fm][fn][reg]);
                }
            }
        }
    }
}

// ==================== pull aggregation (bf16 table, 8-deep MLP) ====================

__global__ __launch_bounds__(256) void agg_pull_256_bf16(
        const int* __restrict__ row_ptr, const int* __restrict__ sorted_src,
        const float* __restrict__ dinv, const unsigned short* __restrict__ Hs,
        const float* __restrict__ bias, unsigned short* __restrict__ outb, int N) {
    int node = blockIdx.x * 4 + (threadIdx.x >> 6);
    int lane = threadIdx.x & 63;
    if (node >= N) return;

    int r0 = row_ptr[node], r1 = row_ptr[node + 1];
    int c = lane << 2;
    ushort4 hv = *(const ushort4*)&Hs[(size_t)node * 256 + c];
    float a0 = bf2f(hv.x), a1 = bf2f(hv.y), a2 = bf2f(hv.z), a3 = bf2f(hv.w);

    int i = r0;
    for (; i + 8 <= r1; i += 8) {
        int s[8];
        #pragma unroll
        for (int u = 0; u < 8; ++u) s[u] = sorted_src[i + u];
        ushort4 h[8];
        #pragma unroll
        for (int u = 0; u < 8; ++u) h[u] = *(const ushort4*)&Hs[(size_t)s[u] * 256 + c];
        #pragma unroll
        for (int u = 0; u < 8; ++u) {
            a0 += bf2f(h[u].x); a1 += bf2f(h[u].y);
            a2 += bf2f(h[u].z); a3 += bf2f(h[u].w);
        }
    }
    if (i + 4 <= r1) {
        int s[4];
        #pragma unroll
        for (int u = 0; u < 4; ++u) s[u] = sorted_src[i + u];
        ushort4 h[4];
        #pragma unroll
        for (int u = 0; u < 4; ++u) h[u] = *(const ushort4*)&Hs[(size_t)s[u] * 256 + c];
        #pragma unroll
        for (int u = 0; u < 4; ++u) {
            a0 += bf2f(h[u].x); a1 += bf2f(h[u].y);
            a2 += bf2f(h[u].z); a3 += bf2f(h[u].w);
        }
        i += 4;
    }
    for (; i < r1; ++i) {
        ushort4 h = *(const ushort4*)&Hs[(size_t)sorted_src[i] * 256 + c];
        a0 += bf2f(h.x); a1 += bf2f(h.y); a2 += bf2f(h.z); a3 += bf2f(h.w);
    }

    float dv = dinv[node];
    float4 bb = *(const float4*)&bias[c];
    float o0 = fmaxf(bb.x + dv * a0, 0.f);
    float o1 = fmaxf(bb.y + dv * a1, 0.f);
    float o2 = fmaxf(bb.z + dv * a2, 0.f);
    float o3 = fmaxf(bb.w + dv * a3, 0.f);
    *(ushort4*)&outb[(size_t)node * 256 + c] = make_ushort4(f2bf(o0), f2bf(o1), f2bf(o2), f2bf(o3));
}

__global__ __launch_bounds__(256) void agg_pull_128_bf16(
        const int* __restrict__ row_ptr, const int* __restrict__ sorted_src,
        const float* __restrict__ dinv, const unsigned short* __restrict__ Hs,
        const float* __restrict__ bias, float* __restrict__ out, int N) {
    int node = blockIdx.x * 4 + (threadIdx.x >> 6);
    int lane = threadIdx.x & 63;
    if (node >= N) return;

    int r0 = row_ptr[node], r1 = row_ptr[node + 1];
    int c = lane << 1;
    ushort2 hv = *(const ushort2*)&Hs[(size_t)node * 128 + c];
    float a0 = bf2f(hv.x), a1 = bf2f(hv.y);

    int i = r0;
    for (; i + 8 <= r1; i += 8) {
        int s[8];
        #pragma unroll
        for (int u = 0; u < 8; ++u) s[u] = sorted_src[i + u];
        ushort2 h[8];
        #pragma unroll
        for (int u = 0; u < 8; ++u) h[u] = *(const ushort2*)&Hs[(size_t)s[u] * 128 + c];
        #pragma unroll
        for (int u = 0; u < 8; ++u) { a0 += bf2f(h[u].x); a1 += bf2f(h[u].y); }
    }
    if (i + 4 <= r1) {
        int s[4];
        #pragma unroll
        for (int u = 0; u < 4; ++u) s[u] = sorted_src[i + u];
        ushort2 h[4];
        #pragma unroll
        for (int u = 0; u < 4; ++u) h[u] = *(const ushort2*)&Hs[(size_t)s[u] * 128 + c];
        #pragma unroll
        for (int u = 0; u < 4; ++u) { a0 += bf2f(h[u].x); a1 += bf2f(h[u].y); }
        i += 4;
    }
    for (; i < r1; ++i) {
        ushort2 h = *(const ushort2*)&Hs[(size_t)sorted_src[i] * 128 + c];
        a0 += bf2f(h.x); a1 += bf2f(h.y);
    }

    float dv = dinv[node];
    float2 bb = *(const float2*)&bias[c];
    *(float2*)&out[(size_t)node * 128 + c] = make_float2(bb.x + dv * a0, bb.y + dv * a1);
}

// ==================== launch ====================

extern "C" void kernel_launch(void* const* d_in, const int* in_sizes, int n_in,
                              void* d_out, int out_size, void* d_ws, size_t ws_size,
                              hipStream_t stream) {
    const float* x   = (const float*)d_in[0];
    const int*   ei  = (const int*)d_in[1];
    const float* W1  = (const float*)d_in[2];
    const float* b1  = (const float*)d_in[3];
    const float* W2  = (const float*)d_in[4];
    const float* b2  = (const float*)d_in[5];
    float* out       = (float*)d_out;

    const int E   = in_sizes[1] / 2;           // 3,200,000
    const int HID = in_sizes[3];               // 256
    const int IN  = in_sizes[2] / HID;         // 256
    const int OUT = in_sizes[5];               // 128
    const int N   = in_sizes[0] / IN;          // 100,000

    char* ws = (char*)d_ws;
    int*   row_ptr    = (int*)ws;                                   // (N+1) ints
    int*   cursor     = (int*)(ws + (512 << 10));
    float* dinv       = (float*)(ws + (1 << 20));
    int*   block_sums = (int*)(ws + 1572864);
    unsigned short* W1b = (unsigned short*)(ws + 1703936);          // 256*256 bf16
    unsigned short* W2b = (unsigned short*)(ws + 1867776);          // 256*128 bf16
    int*   sorted_src = (int*)(ws + (2 << 20));                     // E ints (12.8MB)
    unsigned short* Hsb = (unsigned short*)(ws + ((size_t)16 << 20));  // N*256 bf16 (51.2MB)
    unsigned short* A1b = (unsigned short*)(ws + ((size_t)80 << 20));  // N*256 bf16 (51.2MB)

    const int* e_src = ei;
    const int* e_dst = ei + E;
    const int nb_scan = (N + 255) / 256;

    // ---- CSR build + dinv ----
    hipMemsetAsync(cursor, 0, (size_t)N * sizeof(int), stream);
    deg_count<<<2048, 256, 0, stream>>>(e_dst, cursor, E / 4);
    dinv_kernel<<<nb_scan, 256, 0, stream>>>(cursor, dinv, N);
    scan_blocks<<<nb_scan, 256, 0, stream>>>(cursor, row_ptr, block_sums, N);
    scan_sums<<<1, 512, 0, stream>>>(block_sums, nb_scan);
    scan_add<<<(N + 256) / 256, 256, 0, stream>>>(row_ptr, block_sums, N, E);
    hipMemsetAsync(cursor, 0, (size_t)N * sizeof(int), stream);
    fill_csr<<<4096, 256, 0, stream>>>(e_src, e_dst, row_ptr, cursor, sorted_src, E);

    // ---- weight conversions ----
    f32_to_bf16<<<32, 256, 0, stream>>>(W1, W1b, IN * HID / 4);
    f32_to_bf16<<<16, 256, 0, stream>>>(W2, W2b, HID * OUT / 4);

    // ---- layer 1: Hsb = bf16(dinv * (X@W1)), X read as f32 ----
    gemm_mfma<256, true><<<(N + 63) / 64, 256, 0, stream>>>(x, W1b, Hsb, dinv, N, IN);
    agg_pull_256_bf16<<<(N + 3) / 4, 256, 0, stream>>>(row_ptr, sorted_src, dinv, Hsb, b1, A1b, N);

    // ---- layer 2: Hsb = bf16(dinv * (A1b@W2)) ----
    gemm_mfma<128, false><<<(N + 63) / 64, 256, 0, stream>>>(A1b, W2b, Hsb, dinv, N, HID);
    agg_pull_128_bf16<<<(N + 3) / 4, 256, 0, stream>>>(row_ptr, sorted_src, dinv, Hsb, b2, out, N);
}